// Round 3
// baseline (84.697 us; speedup 1.0000x reference)
//
#include <hip/hip_runtime.h>

// SpatiallyJitterColorChannels: per-(b,c) 2D roll of x[64,3,512,512] f32.
// out[b,c,h,w] = x[b,c,(h-sh)&511,(w-sw)&511], s = shifts[b,c,:] - SHIFT
#define SHIFT 2
#define H 512
#define W 512

// LDS-free version: the column roll is wave-uniform and tiny (|sw|<=2), so
// each output float4 is read directly from global at the shifted address as
// an unaligned-but-contiguous 16B load (dword alignment suffices on gfx950;
// worst case the backend splits into 4 dword loads that still coalesce).
// Row-edge quads that wrap around the 512-float row take a rare exec-masked
// scalar path. All reads stay inside the row -> exact HBM traffic. Stores
// remain 16B-aligned.

typedef float f4 __attribute__((ext_vector_type(4)));
typedef f4 __attribute__((aligned(4))) f4_unaligned;

__global__ __launch_bounds__(256)
void roll2d_kernel(const float* __restrict__ x,
                   const int* __restrict__ shifts,
                   float* __restrict__ out) {
    const int tid  = threadIdx.x;
    const int wv   = tid >> 6;    // 0..3
    const int lane = tid & 63;
    const int bc   = blockIdx.y;  // 0..191 (b*3+c), uniform -> scalar loads

    const int sh = shifts[2 * bc]     - SHIFT;  // [-2,2]
    const int sw = shifts[2 * bc + 1] - SHIFT;  // [-2,2]

    const size_t plane = (size_t)bc * (H * W);
    const float* __restrict__ xin = x   + plane;
    float*       __restrict__ xo  = out + plane;

    const int h0 = blockIdx.x * 16 + wv * 4;   // 4 rows per wave

#pragma unroll
    for (int r = 0; r < 4; ++r) {
        const int h = h0 + r;
        const float* __restrict__ src = xin + ((h - sh) & (H - 1)) * W;
        float*       __restrict__ dst = xo  + h * W;
#pragma unroll
        for (int c = 0; c < 2; ++c) {
            const int w0   = 4 * (lane + 64 * c);  // output quad start
            const int base = w0 - sw;              // [-2, 509]
            f4 o;
            if (base >= 0 && base <= W - 4) {
                // common path: contiguous unaligned 16B load within the row
                o = *reinterpret_cast<const f4_unaligned*>(src + base);
            } else {
                // row-edge wrap (at most 1 lane per chunk, only when sw != 0)
                o.x = src[(base + 0) & (W - 1)];
                o.y = src[(base + 1) & (W - 1)];
                o.z = src[(base + 2) & (W - 1)];
                o.w = src[(base + 3) & (W - 1)];
            }
            *reinterpret_cast<f4*>(dst + w0) = o;
        }
    }
}

extern "C" void kernel_launch(void* const* d_in, const int* in_sizes, int n_in,
                              void* d_out, int out_size, void* d_ws, size_t ws_size,
                              hipStream_t stream) {
    const float* x      = (const float*)d_in[0];   // [64,3,512,512] f32
    const int*   shifts = (const int*)d_in[1];     // [64,3,2] i32
    float*       out    = (float*)d_out;           // [64,3,512,512] f32

    dim3 grid(H / 16, 64 * 3);   // 16 rows per block (4 waves x 4 rows)
    dim3 block(256);
    roll2d_kernel<<<grid, block, 0, stream>>>(x, shifts, out);
}

// Round 5
// 76.896 us; speedup vs baseline: 1.1014x; 1.1014x over previous
//
#include <hip/hip_runtime.h>

// SpatiallyJitterColorChannels: per-(b,c) 2D roll of x[64,3,512,512] f32.
// out[b,c,h,w] = x[b,c,(h-sh)&511,(w-sw)&511], s = shifts[b,c,:] - SHIFT
#define SHIFT 2
#define H 512
#define W 512
#define QPR (W / 4)   // 128 quads per row

// Aligned-only, LDS-free: each lane loads its own aligned quad plus the
// (aligned) adjacent quad, and assembles the shifted output quad with a
// hardcoded component permute chosen by a wave-uniform scalar branch on sw.
// The adjacent-quad load re-reads lines the wave already fetched -> L1 hit,
// HBM traffic unchanged. All global loads/stores are 16B-aligned.

__global__ __launch_bounds__(256)
void roll2d_kernel(const float* __restrict__ x,
                   const int* __restrict__ shifts,
                   float* __restrict__ out) {
    const int tid  = threadIdx.x;
    const int wv   = tid >> 6;    // 0..3
    const int lane = tid & 63;
    const int bc   = blockIdx.y;  // 0..191 (b*3+c), uniform

    // Force shifts into SGPRs -> scalar branches below (no divergence).
    const int sh = __builtin_amdgcn_readfirstlane(shifts[2 * bc])     - SHIFT;
    const int sw = __builtin_amdgcn_readfirstlane(shifts[2 * bc + 1]) - SHIFT;

    const size_t plane = (size_t)bc * (H * W);
    const float* __restrict__ xin = x   + plane;
    float*       __restrict__ xo  = out + plane;

    const int hbase = blockIdx.x * 16 + wv * 4;   // 4 rows per wave

#define ROW_SETUP(r)                                                        \
    const int h##r = hbase + r;                                             \
    const float4* __restrict__ s##r = reinterpret_cast<const float4*>(      \
        xin + ((h##r - sh) & (H - 1)) * (size_t)W);                         \
    float4* __restrict__ d##r = reinterpret_cast<float4*>(xo + h##r * (size_t)W);

    ROW_SETUP(0) ROW_SETUP(1) ROW_SETUP(2) ROW_SETUP(3)

    if (sw == 0) {
        // pure aligned copy
#pragma unroll
        for (int c = 0; c < 2; ++c) {
            const int k = lane + 64 * c;
            float4 c0 = s0[k], c1 = s1[k], c2 = s2[k], c3 = s3[k];
            d0[k] = c0; d1[k] = c1; d2[k] = c2; d3[k] = c3;
        }
    } else if (sw > 0) {
        const int swi = sw;  // 1 or 2
#pragma unroll
        for (int c = 0; c < 2; ++c) {
            const int k  = lane + 64 * c;
            const int kp = (k + QPR - 1) & (QPR - 1);
            float4 c0 = s0[k], p0 = s0[kp];
            float4 c1 = s1[k], p1 = s1[kp];
            float4 c2 = s2[k], p2 = s2[kp];
            float4 c3 = s3[k], p3 = s3[kp];
            if (swi == 1) {
                d0[k] = make_float4(p0.w, c0.x, c0.y, c0.z);
                d1[k] = make_float4(p1.w, c1.x, c1.y, c1.z);
                d2[k] = make_float4(p2.w, c2.x, c2.y, c2.z);
                d3[k] = make_float4(p3.w, c3.x, c3.y, c3.z);
            } else {
                d0[k] = make_float4(p0.z, p0.w, c0.x, c0.y);
                d1[k] = make_float4(p1.z, p1.w, c1.x, c1.y);
                d2[k] = make_float4(p2.z, p2.w, c2.x, c2.y);
                d3[k] = make_float4(p3.z, p3.w, c3.x, c3.y);
            }
        }
    } else {
        const int swi = -sw;  // 1 or 2
#pragma unroll
        for (int c = 0; c < 2; ++c) {
            const int k  = lane + 64 * c;
            const int kn = (k + 1) & (QPR - 1);
            float4 c0 = s0[k], n0 = s0[kn];
            float4 c1 = s1[k], n1 = s1[kn];
            float4 c2 = s2[k], n2 = s2[kn];
            float4 c3 = s3[k], n3 = s3[kn];
            if (swi == 1) {
                d0[k] = make_float4(c0.y, c0.z, c0.w, n0.x);
                d1[k] = make_float4(c1.y, c1.z, c1.w, n1.x);
                d2[k] = make_float4(c2.y, c2.z, c2.w, n2.x);
                d3[k] = make_float4(c3.y, c3.z, c3.w, n3.x);
            } else {
                d0[k] = make_float4(c0.z, c0.w, n0.x, n0.y);
                d1[k] = make_float4(c1.z, c1.w, n1.x, n1.y);
                d2[k] = make_float4(c2.z, c2.w, n2.x, n2.y);
                d3[k] = make_float4(c3.z, c3.w, n3.x, n3.y);
            }
        }
    }
#undef ROW_SETUP
}

extern "C" void kernel_launch(void* const* d_in, const int* in_sizes, int n_in,
                              void* d_out, int out_size, void* d_ws, size_t ws_size,
                              hipStream_t stream) {
    const float* x      = (const float*)d_in[0];   // [64,3,512,512] f32
    const int*   shifts = (const int*)d_in[1];     // [64,3,2] i32
    float*       out    = (float*)d_out;           // [64,3,512,512] f32

    dim3 grid(H / 16, 64 * 3);   // 16 rows per block (4 waves x 4 rows)
    dim3 block(256);
    roll2d_kernel<<<grid, block, 0, stream>>>(x, shifts, out);
}

// Round 7
// 63.399 us; speedup vs baseline: 1.3359x; 1.2129x over previous
//
#include <hip/hip_runtime.h>

// SpatiallyJitterColorChannels: per-(b,c) 2D roll of x[64,3,512,512] f32.
// out[b,c,h,w] = x[b,c,(h-sh)&511,(w-sw)&511], s = shifts[b,c,:] - SHIFT
#define SHIFT 2
#define H 512
#define W 512
#define QPR (W / 4)   // 128 quads per row

// Round-5 structure (aligned-only loads, wave-uniform permute on sw, no LDS)
// + NON-TEMPORAL STORES via clang ext-vector float4 (HIP float4 struct is
// rejected by __builtin_nontemporal_store). Output is never re-read, so `nt`
// stores avoid write-allocate pollution of L2/L3, leaving Infinity Cache for
// the 192MB input read stream.

typedef float f4 __attribute__((ext_vector_type(4)));

static __device__ __forceinline__ f4 mkf4(float a, float b, float c, float d) {
    f4 r; r.x = a; r.y = b; r.z = c; r.w = d; return r;
}

__global__ __launch_bounds__(256)
void roll2d_kernel(const float* __restrict__ x,
                   const int* __restrict__ shifts,
                   float* __restrict__ out) {
    const int tid  = threadIdx.x;
    const int wv   = tid >> 6;    // 0..3
    const int lane = tid & 63;
    const int bc   = blockIdx.y;  // 0..191 (b*3+c), uniform

    // Force shifts into SGPRs -> scalar branches below (no divergence).
    const int sh = __builtin_amdgcn_readfirstlane(shifts[2 * bc])     - SHIFT;
    const int sw = __builtin_amdgcn_readfirstlane(shifts[2 * bc + 1]) - SHIFT;

    const size_t plane = (size_t)bc * (H * W);
    const float* __restrict__ xin = x   + plane;
    float*       __restrict__ xo  = out + plane;

    const int hbase = blockIdx.x * 16 + wv * 4;   // 4 rows per wave

#define ROW_SETUP(r)                                                        \
    const int h##r = hbase + r;                                             \
    const f4* __restrict__ s##r = reinterpret_cast<const f4*>(              \
        xin + ((h##r - sh) & (H - 1)) * (size_t)W);                         \
    f4* __restrict__ d##r = reinterpret_cast<f4*>(xo + h##r * (size_t)W);

    ROW_SETUP(0) ROW_SETUP(1) ROW_SETUP(2) ROW_SETUP(3)

#define NTSTORE(p, v) __builtin_nontemporal_store((v), (p))

    if (sw == 0) {
        // pure aligned copy
#pragma unroll
        for (int c = 0; c < 2; ++c) {
            const int k = lane + 64 * c;
            f4 c0 = s0[k], c1 = s1[k], c2 = s2[k], c3 = s3[k];
            NTSTORE(&d0[k], c0); NTSTORE(&d1[k], c1);
            NTSTORE(&d2[k], c2); NTSTORE(&d3[k], c3);
        }
    } else if (sw > 0) {
        const int swi = sw;  // 1 or 2
#pragma unroll
        for (int c = 0; c < 2; ++c) {
            const int k  = lane + 64 * c;
            const int kp = (k + QPR - 1) & (QPR - 1);
            f4 c0 = s0[k], p0 = s0[kp];
            f4 c1 = s1[k], p1 = s1[kp];
            f4 c2 = s2[k], p2 = s2[kp];
            f4 c3 = s3[k], p3 = s3[kp];
            if (swi == 1) {
                NTSTORE(&d0[k], mkf4(p0.w, c0.x, c0.y, c0.z));
                NTSTORE(&d1[k], mkf4(p1.w, c1.x, c1.y, c1.z));
                NTSTORE(&d2[k], mkf4(p2.w, c2.x, c2.y, c2.z));
                NTSTORE(&d3[k], mkf4(p3.w, c3.x, c3.y, c3.z));
            } else {
                NTSTORE(&d0[k], mkf4(p0.z, p0.w, c0.x, c0.y));
                NTSTORE(&d1[k], mkf4(p1.z, p1.w, c1.x, c1.y));
                NTSTORE(&d2[k], mkf4(p2.z, p2.w, c2.x, c2.y));
                NTSTORE(&d3[k], mkf4(p3.z, p3.w, c3.x, c3.y));
            }
        }
    } else {
        const int swi = -sw;  // 1 or 2
#pragma unroll
        for (int c = 0; c < 2; ++c) {
            const int k  = lane + 64 * c;
            const int kn = (k + 1) & (QPR - 1);
            f4 c0 = s0[k], n0 = s0[kn];
            f4 c1 = s1[k], n1 = s1[kn];
            f4 c2 = s2[k], n2 = s2[kn];
            f4 c3 = s3[k], n3 = s3[kn];
            if (swi == 1) {
                NTSTORE(&d0[k], mkf4(c0.y, c0.z, c0.w, n0.x));
                NTSTORE(&d1[k], mkf4(c1.y, c1.z, c1.w, n1.x));
                NTSTORE(&d2[k], mkf4(c2.y, c2.z, c2.w, n2.x));
                NTSTORE(&d3[k], mkf4(c3.y, c3.z, c3.w, n3.x));
            } else {
                NTSTORE(&d0[k], mkf4(c0.z, c0.w, n0.x, n0.y));
                NTSTORE(&d1[k], mkf4(c1.z, c1.w, n1.x, n1.y));
                NTSTORE(&d2[k], mkf4(c2.z, c2.w, n2.x, n2.y));
                NTSTORE(&d3[k], mkf4(c3.z, c3.w, n3.x, n3.y));
            }
        }
    }
#undef ROW_SETUP
#undef NTSTORE
}

extern "C" void kernel_launch(void* const* d_in, const int* in_sizes, int n_in,
                              void* d_out, int out_size, void* d_ws, size_t ws_size,
                              hipStream_t stream) {
    const float* x      = (const float*)d_in[0];   // [64,3,512,512] f32
    const int*   shifts = (const int*)d_in[1];     // [64,3,2] i32
    float*       out    = (float*)d_out;           // [64,3,512,512] f32

    dim3 grid(H / 16, 64 * 3);   // 16 rows per block (4 waves x 4 rows)
    dim3 block(256);
    roll2d_kernel<<<grid, block, 0, stream>>>(x, shifts, out);
}